// Round 4
// baseline (411.381 us; speedup 1.0000x reference)
//
#include <hip/hip_runtime.h>
#include <hip/hip_bf16.h>
#include <stdint.h>

typedef __bf16 bf16x8 __attribute__((ext_vector_type(8)));
typedef float f32x4 __attribute__((ext_vector_type(4)));

// ---------------- helpers ----------------

__device__ __forceinline__ void gld_lds16(const void* g, void* l) {
  // global -> LDS direct DMA, 16B per lane (wave-uniform base + lane*16).
  __builtin_amdgcn_global_load_lds(
      (const __attribute__((address_space(1))) unsigned int*)g,
      (__attribute__((address_space(3))) unsigned int*)l, 16, 0, 0);
}

__device__ __forceinline__ uint16_t f2bf(float f) {
  uint32_t u = __float_as_uint(f);
  return (uint16_t)((u + 0x7fffu + ((u >> 16) & 1u)) >> 16);
}

__device__ __forceinline__ uint32_t pk2(float a, float b) {
  return (uint32_t)f2bf(a) | ((uint32_t)f2bf(b) << 16);
}

__device__ __forceinline__ uint32_t pkbf(float a, float b) {
  // RNE pack of two fp32 -> packed bf16x2; lowers to v_cvt_pk_bf16_f32 where
  // available, else the shift/round sequence.
  __hip_bfloat162 h = __float22bfloat162_rn(make_float2(a, b));
  union { __hip_bfloat162 h2; uint32_t u; } cv;
  cv.h2 = h;
  return cv.u;
}

// ---------------- cast fp32 -> bf16 with K zero-padding (B only) ------------
__global__ void cast_pad_kernel(const float* __restrict__ in,
                                uint16_t* __restrict__ out,
                                int rows, int cin, int cout) {
  int64_t idx = (int64_t)blockIdx.x * 256 + threadIdx.x;
  int perRow = cout >> 3;
  int64_t total = (int64_t)rows * perRow;
  if (idx >= total) return;
  int r = (int)(idx / perRow);
  int k = ((int)(idx % perRow)) << 3;
  uint4 v;
  if (k < cin) {
    const float4* p = (const float4*)(in + (int64_t)r * cin + k);
    float4 f0 = p[0], f1 = p[1];
    v = make_uint4(pk2(f0.x, f0.y), pk2(f0.z, f0.w),
                   pk2(f1.x, f1.y), pk2(f1.z, f1.w));
  } else {
    v = make_uint4(0u, 0u, 0u, 0u);
  }
  *(uint4*)(out + (int64_t)r * cout + k) = v;
}

// ---------------- GEMM1 fused: P_z[M,N] = A_fp32[M,K] * B_bf16[N,K]^T -------
// 128x128 tile, BK=64, 4 waves 2x2, XOR-swizzled LDS (0 conflicts, verified
// round 2). A is cast fp32->bf16 during staging (VGPR round-trip); B staged
// via DMA from the pre-cast Wb. z in {0,1,2} selects a K-chunk (27/26/26
// iters of 64) and a private output buffer (no atomics).
// K raw = 5000: groups starting >= 5000 clamp source to col 0; B is
// zero-padded to 5056 so those lanes contribute exactly 0.
__global__ __launch_bounds__(256, 3) void gemm1_fused(
    const float* __restrict__ A,       // [8192][5000] fp32
    const uint16_t* __restrict__ Bm,   // [512][5056] bf16 (zero-padded)
    float* __restrict__ P) {           // [3][8192][512] partials
  __shared__ __align__(16) uint16_t As[128 * 64];
  __shared__ __align__(16) uint16_t Bs[128 * 64];
  const int tid = threadIdx.x;
  const int lane = tid & 63;
  const int wid = tid >> 6;
  const int wm = wid >> 1, wn = wid & 1;

  const int lin = blockIdx.x;
  const int mlo = lin & 7;
  const int nbk = (lin >> 3) & 3;
  const int rest = lin >> 5;           // 0..23
  const int mhi = rest & 7;
  const int z = rest >> 3;             // 0..2
  const int m0 = (mhi * 8 + mlo) * 128;
  const int n0 = nbk * 128;
  const int it0 = (z == 0) ? 0 : (27 + 26 * (z - 1));
  const int itN = (z == 0) ? 27 : 26;

  // A staging assignment: thread handles row (tid>>1), chunk-half (tid&1).
  const int arow = tid >> 1;
  const int ahalf = tid & 1;
  const int akey = arow & 7;
  const float* Arow = A + (int64_t)(m0 + arow) * 5000;

  // B staging (DMA): 32 rows per call, swizzled source column.
  const int srow = tid >> 3;
  const int skswz = ((tid & 7) ^ (srow & 7)) << 3;
  const uint16_t* Bb = Bm + (int64_t)(n0 + srow) * 5056 + skswz;

  const int lrow = lane & 15;
  const int key = lrow & 7;
  const int kg = lane >> 4;

  f32x4 acc[4][4] = {};

  for (int it = 0; it < itN; ++it) {
    const int kt = (it0 + it) << 6;
    // B: async DMA into swizzled LDS
#pragma unroll
    for (int p = 0; p < 4; ++p)
      gld_lds16(Bb + (int64_t)(p * 32) * 5056 + kt, &Bs[(p * 256 + tid) * 8]);
    // A: global fp32 -> VGPR -> bf16 pack -> LDS (same swizzled layout)
#pragma unroll
    for (int q = 0; q < 4; ++q) {
      const int c = ahalf * 4 + q;          // chunk 0..7 within row
      const int g = c ^ akey;               // global 8-float group
      const int col = kt + (g << 3);
      const float4* s = (const float4*)(Arow + (col < 5000 ? col : 0));
      float4 f0 = s[0], f1 = s[1];
      uint4 v = make_uint4(pkbf(f0.x, f0.y), pkbf(f0.z, f0.w),
                           pkbf(f1.x, f1.y), pkbf(f1.z, f1.w));
      *(uint4*)&As[arow * 64 + c * 8] = v;
    }
    __syncthreads();
#pragma unroll
    for (int ks = 0; ks < 2; ++ks) {
      const int off = (((ks << 2) | kg) ^ key) << 3;
      bf16x8 af[4], bfr[4];
#pragma unroll
      for (int i = 0; i < 4; ++i)
        af[i] = *(const bf16x8*)&As[(wm * 64 + i * 16 + lrow) * 64 + off];
#pragma unroll
      for (int j = 0; j < 4; ++j)
        bfr[j] = *(const bf16x8*)&Bs[(wn * 64 + j * 16 + lrow) * 64 + off];
#pragma unroll
      for (int i = 0; i < 4; ++i)
#pragma unroll
        for (int j = 0; j < 4; ++j)
          acc[i][j] = __builtin_amdgcn_mfma_f32_16x16x32_bf16(af[i], bfr[j],
                                                              acc[i][j], 0, 0, 0);
    }
    __syncthreads();
  }

  float* Pz = P + (int64_t)z * 8192 * 512;
  const int r0 = (lane >> 4) << 2;
#pragma unroll
  for (int i = 0; i < 4; ++i) {
    int row = m0 + wm * 64 + i * 16 + r0;
#pragma unroll
    for (int j = 0; j < 4; ++j) {
      int col = n0 + wn * 64 + j * 16 + (lane & 15);
      float* cp = Pz + (int64_t)row * 512 + col;
#pragma unroll
      for (int r = 0; r < 4; ++r) cp[(int64_t)r * 512] = acc[i][j][r];
    }
  }
}

// ---------------- V[h][t] = sum_k CM[t][h][k] * cla_w[k] ----------------
__global__ __launch_bounds__(256) void cmv_kernel(const float* __restrict__ CM,
                                                  const float* __restrict__ cla_w,
                                                  float* __restrict__ Vs) {
  const int tid = threadIdx.x, lane = tid & 63, wid = tid >> 6;
  const int row = blockIdx.x * 4 + wid;  // 0..8191 = t*512 + h
  const float4* src = (const float4*)(CM + (int64_t)row * 512);
  const float4* cw = (const float4*)cla_w;
  float4 a0 = src[lane * 2], a1 = src[lane * 2 + 1];
  float4 w0 = cw[lane * 2], w1 = cw[lane * 2 + 1];
  float s = a0.x * w0.x + a0.y * w0.y + a0.z * w0.z + a0.w * w0.w +
            a1.x * w1.x + a1.y * w1.y + a1.z * w1.z + a1.w * w1.w;
#pragma unroll
  for (int o = 32; o >= 1; o >>= 1) s += __shfl_xor(s, o);
  if (lane == 0) {
    int t = row >> 9, h = row & 511;
    Vs[h * 16 + t] = s;
  }
}

// ------- fused epilogue: sum partials + bias, scores, softmax, y=x.V,
//         sigmoid(w.y + b). 16 batch rows per block. -------
__global__ __launch_bounds__(256) void attn_final(
    const float* __restrict__ P,      // [3][8192][512] partials
    const float* __restrict__ bias,   // [512]
    const float* __restrict__ attn, const float* __restrict__ Vs,
    const float* __restrict__ cla_b, float* __restrict__ out) {
  __shared__ float xs[16 * 512];   // 32 KB
  __shared__ float avs[256 * 32];  // 32 KB
  const int tid = threadIdx.x;
  const int b0 = blockIdx.x * 16;
  const int64_t base4 = (int64_t)b0 * 128;  // float4 index of row b0
  const float4* P0 = (const float4*)P;
  const float4* P1 = P0 + (int64_t)8192 * 128;
  const float4* P2 = P1 + (int64_t)8192 * 128;
  const float4* b4 = (const float4*)bias;
#pragma unroll
  for (int p = 0; p < 8; ++p) {
    int e4 = p * 256 + tid;
    float4 a = P0[base4 + e4], b = P1[base4 + e4], c = P2[base4 + e4];
    float4 bb = b4[e4 & 127];
    float4 r;
    r.x = a.x + b.x + c.x + bb.x;
    r.y = a.y + b.y + c.y + bb.y;
    r.z = a.z + b.z + c.z + bb.z;
    r.w = a.w + b.w + c.w + bb.w;
    ((float4*)xs)[e4] = r;
  }
  const int lane = tid & 63, w = tid >> 6;
  const int bl = w * 4 + (lane >> 4);
  const int t = lane & 15;
  const float* xr = xs + bl * 512;
  float s = 0.f, y = 0.f;
  for (int ph = 0; ph < 2; ++ph) {
    __syncthreads();
#pragma unroll
    for (int p = 0; p < 4; ++p) {
      int e4 = p * 256 + tid;  // 1024 float4 = 256 h-rows x 16
      int h = e4 >> 2, c = (e4 & 3) << 2;
      *(float4*)&avs[h * 32 + c] = ((const float4*)attn)[ph * 1024 + e4];
      *(float4*)&avs[h * 32 + 16 + c] = ((const float4*)Vs)[ph * 1024 + e4];
    }
    __syncthreads();
    const float* xp = xr + ph * 256;
#pragma unroll 4
    for (int h = 0; h < 256; ++h) {
      float xv = xp[h];
      s += xv * avs[h * 32 + t];
      y += xv * avs[h * 32 + 16 + t];
    }
  }
  float m = s;
#pragma unroll
  for (int o = 8; o >= 1; o >>= 1) m = fmaxf(m, __shfl_xor(m, o));
  float e = __expf(s - m);
  float sum = e;
#pragma unroll
  for (int o = 8; o >= 1; o >>= 1) sum += __shfl_xor(sum, o);
  float val = (e / sum) * y;
#pragma unroll
  for (int o = 8; o >= 1; o >>= 1) val += __shfl_xor(val, o);
  if (t == 0) out[b0 + bl] = 1.f / (1.f + __expf(-(val + cla_b[0])));
}

// ---------------- launch ----------------
extern "C" void kernel_launch(void* const* d_in, const int* in_sizes, int n_in,
                              void* d_out, int out_size, void* d_ws,
                              size_t ws_size, hipStream_t stream) {
  const float* data = (const float*)d_in[0];   // [8192][5000]
  const float* mlp_w = (const float*)d_in[1];  // [512][5000]
  const float* mlp_b = (const float*)d_in[2];  // [512]
  const float* CM = (const float*)d_in[3];     // [16][512][512]
  const float* attn = (const float*)d_in[4];   // [512][16]
  const float* cla_w = (const float*)d_in[5];  // [512]
  const float* cla_b = (const float*)d_in[6];  // [1]
  float* out = (float*)d_out;                  // [8192]

  char* ws = (char*)d_ws;
  uint16_t* Wb = (uint16_t*)(ws + 0);          // 512*5056*2  =  5,177,344
  float* P = (float*)(ws + 5177344);           // 3*8192*512*4 = 50,331,648
  float* Vs = (float*)(ws + 55508992);         // 512*16*4 = 32,768
  // total: 55,541,760 bytes (well under prior 106 MB footprint)

  // 1) B: cast + zero-pad K 5000 -> 5056 (79*64)
  cast_pad_kernel<<<1264, 256, 0, stream>>>(mlp_w, Wb, 512, 5000, 5056);
  // 2) V = CM . cla_w
  cmv_kernel<<<2048, 256, 0, stream>>>(CM, cla_w, Vs);
  // 3) fused cast+GEMM1, z-split into 3 partial buffers (no atomics)
  gemm1_fused<<<768, 256, 0, stream>>>(data, Wb, P);
  // 4) fused partial-sum + bias + softmax + mixture-collapse + sigmoid
  attn_final<<<512, 256, 0, stream>>>(P, mlp_b, attn, Vs, cla_b, out);
}

// Round 5
// 404.547 us; speedup vs baseline: 1.0169x; 1.0169x over previous
//
#include <hip/hip_runtime.h>
#include <hip/hip_bf16.h>
#include <stdint.h>

typedef __bf16 bf16x8 __attribute__((ext_vector_type(8)));
typedef float f32x4 __attribute__((ext_vector_type(4)));

// ---------------- helpers ----------------

__device__ __forceinline__ void gld_lds16(const void* g, void* l) {
  // global -> LDS direct DMA, 16B per lane (wave-uniform base + lane*16).
  __builtin_amdgcn_global_load_lds(
      (const __attribute__((address_space(1))) unsigned int*)g,
      (__attribute__((address_space(3))) unsigned int*)l, 16, 0, 0);
}

__device__ __forceinline__ uint16_t f2bf(float f) {
  uint32_t u = __float_as_uint(f);
  return (uint16_t)((u + 0x7fffu + ((u >> 16) & 1u)) >> 16);
}

__device__ __forceinline__ uint32_t pk2(float a, float b) {
  return (uint32_t)f2bf(a) | ((uint32_t)f2bf(b) << 16);
}

union BF8U {
  uint32_t u[4];
  bf16x8 v;
};

__device__ __forceinline__ bf16x8 pack8(float4 f0, float4 f1) {
  BF8U r;
  r.u[0] = pk2(f0.x, f0.y);
  r.u[1] = pk2(f0.z, f0.w);
  r.u[2] = pk2(f1.x, f1.y);
  r.u[3] = pk2(f1.z, f1.w);
  return r.v;
}

// ---------------- cast fp32 -> bf16 with K zero-padding (B only) ------------
__global__ void cast_pad_kernel(const float* __restrict__ in,
                                uint16_t* __restrict__ out,
                                int rows, int cin, int cout) {
  int64_t idx = (int64_t)blockIdx.x * 256 + threadIdx.x;
  int perRow = cout >> 3;
  int64_t total = (int64_t)rows * perRow;
  if (idx >= total) return;
  int r = (int)(idx / perRow);
  int k = ((int)(idx % perRow)) << 3;
  uint4 v;
  if (k < cin) {  // cin % 8 == 0 so never straddles
    const float4* p = (const float4*)(in + (int64_t)r * cin + k);
    float4 f0 = p[0], f1 = p[1];
    v = make_uint4(pk2(f0.x, f0.y), pk2(f0.z, f0.w),
                   pk2(f1.x, f1.y), pk2(f1.z, f1.w));
  } else {
    v = make_uint4(0u, 0u, 0u, 0u);
  }
  *(uint4*)(out + (int64_t)r * cout + k) = v;
}

// ---------------- GEMM1 direct-A: P_z = A_fp32[M,K] * B_bf16[N,K]^T ---------
// 128x128 tile, BK=64, 4 waves 2x2. A fragments loaded straight from global
// fp32 (32 B/lane, 16x128B coalesced segments per instruction) and packed to
// bf16 in VGPRs -- A never touches LDS (round-4's ds_write conflicts are
// structurally gone). B keeps the verified DMA + XOR-swizzle path (0 bank
// conflicts, rounds 2-3). z in {0,1,2} picks a K-chunk (27/26/26 iters) and a
// private partial buffer (no atomics). B zero-padded to 5056, so A tail
// garbage (clamped addresses) is annihilated by B zeros.
__global__ __launch_bounds__(256, 3) void gemm1_direct(
    const float* __restrict__ A,       // [8192][5000] fp32
    const uint16_t* __restrict__ Bm,   // [512][5056] bf16 (zero-padded)
    float* __restrict__ P) {           // [3][8192][512] partials
  __shared__ __align__(16) uint16_t Bs[128 * 64];
  const int tid = threadIdx.x;
  const int lane = tid & 63;
  const int wid = tid >> 6;
  const int wm = wid >> 1, wn = wid & 1;

  // decode: n-siblings of one (m,z) stripe sit at stride 8 -> same XCD
  const int lin = blockIdx.x;
  const int mlo = lin & 7;
  const int nbk = (lin >> 3) & 3;
  const int rest = lin >> 5;  // 0..23
  const int mhi = rest & 7;
  const int z = rest >> 3;    // 0..2
  const int m0 = (mhi * 8 + mlo) * 128;
  const int n0 = nbk * 128;
  const int it0 = (z == 0) ? 0 : (27 + 26 * (z - 1));
  const int itN = (z == 0) ? 27 : 26;

  // B staging (DMA, swizzled): 32 rows per call
  const int srow = tid >> 3;
  const int skswz = ((tid & 7) ^ (srow & 7)) << 3;
  const uint16_t* Bb = Bm + (int64_t)(n0 + srow) * 5056 + skswz;

  const int lrow = lane & 15;
  const int key = lrow & 7;
  const int kg = lane >> 4;

  // per-lane A row base (m-tile i adds i*16 rows)
  const float* Ar = A + (int64_t)(m0 + wm * 64 + lrow) * 5000;

  f32x4 acc[4][4] = {};

  for (int it = 0; it < itN; ++it) {
    const int kt = (it0 + it) << 6;
    // B: async DMA into swizzled LDS (in flight during A loads)
#pragma unroll
    for (int p = 0; p < 4; ++p)
      gld_lds16(Bb + (int64_t)(p * 32) * 5056 + kt, &Bs[(p * 256 + tid) * 8]);
    // A: direct global fp32 -> bf16 fragments (no LDS)
    bf16x8 af[4][2];
#pragma unroll
    for (int i = 0; i < 4; ++i)
#pragma unroll
      for (int ks = 0; ks < 2; ++ks) {
        const int col = kt + ks * 32 + kg * 8;
        const float4* s =
            (const float4*)(Ar + (int64_t)i * (16 * 5000) + (col < 5000 ? col : 0));
        float4 f0 = s[0], f1 = s[1];
        af[i][ks] = pack8(f0, f1);
      }
    __syncthreads();
#pragma unroll
    for (int ks = 0; ks < 2; ++ks) {
      const int off = (((ks << 2) | kg) ^ key) << 3;
      bf16x8 bfr[4];
#pragma unroll
      for (int j = 0; j < 4; ++j)
        bfr[j] = *(const bf16x8*)&Bs[(wn * 64 + j * 16 + lrow) * 64 + off];
#pragma unroll
      for (int i = 0; i < 4; ++i)
#pragma unroll
        for (int j = 0; j < 4; ++j)
          acc[i][j] = __builtin_amdgcn_mfma_f32_16x16x32_bf16(
              af[i][ks], bfr[j], acc[i][j], 0, 0, 0);
    }
    __syncthreads();
  }

  float* Pz = P + (int64_t)z * 8192 * 512;
  const int r0 = (lane >> 4) << 2;
#pragma unroll
  for (int i = 0; i < 4; ++i) {
    int row = m0 + wm * 64 + i * 16 + r0;
#pragma unroll
    for (int j = 0; j < 4; ++j) {
      int col = n0 + wn * 64 + j * 16 + (lane & 15);
      float* cp = Pz + (int64_t)row * 512 + col;
#pragma unroll
      for (int r = 0; r < 4; ++r) cp[(int64_t)r * 512] = acc[i][j][r];
    }
  }
}

// ---------------- V[h][t] = sum_k CM[t][h][k] * cla_w[k] ----------------
__global__ __launch_bounds__(256) void cmv_kernel(const float* __restrict__ CM,
                                                  const float* __restrict__ cla_w,
                                                  float* __restrict__ Vs) {
  const int tid = threadIdx.x, lane = tid & 63, wid = tid >> 6;
  const int row = blockIdx.x * 4 + wid;  // 0..8191 = t*512 + h
  const float4* src = (const float4*)(CM + (int64_t)row * 512);
  const float4* cw = (const float4*)cla_w;
  float4 a0 = src[lane * 2], a1 = src[lane * 2 + 1];
  float4 w0 = cw[lane * 2], w1 = cw[lane * 2 + 1];
  float s = a0.x * w0.x + a0.y * w0.y + a0.z * w0.z + a0.w * w0.w +
            a1.x * w1.x + a1.y * w1.y + a1.z * w1.z + a1.w * w1.w;
#pragma unroll
  for (int o = 32; o >= 1; o >>= 1) s += __shfl_xor(s, o);
  if (lane == 0) {
    int t = row >> 9, h = row & 511;
    Vs[h * 16 + t] = s;
  }
}

// ------- fused epilogue: sum partials + bias, scores, softmax, y=x.V,
//         sigmoid(w.y + b). 16 batch rows per block. -------
__global__ __launch_bounds__(256) void attn_final(
    const float* __restrict__ P,      // [3][8192][512] partials
    const float* __restrict__ bias,   // [512]
    const float* __restrict__ attn, const float* __restrict__ Vs,
    const float* __restrict__ cla_b, float* __restrict__ out) {
  __shared__ float xs[16 * 512];   // 32 KB
  __shared__ float avs[256 * 32];  // 32 KB
  const int tid = threadIdx.x;
  const int b0 = blockIdx.x * 16;
  const int64_t base4 = (int64_t)b0 * 128;
  const float4* P0 = (const float4*)P;
  const float4* P1 = P0 + (int64_t)8192 * 128;
  const float4* P2 = P1 + (int64_t)8192 * 128;
  const float4* b4 = (const float4*)bias;
#pragma unroll
  for (int p = 0; p < 8; ++p) {
    int e4 = p * 256 + tid;
    float4 a = P0[base4 + e4], b = P1[base4 + e4], c = P2[base4 + e4];
    float4 bb = b4[e4 & 127];
    float4 r;
    r.x = a.x + b.x + c.x + bb.x;
    r.y = a.y + b.y + c.y + bb.y;
    r.z = a.z + b.z + c.z + bb.z;
    r.w = a.w + b.w + c.w + bb.w;
    ((float4*)xs)[e4] = r;
  }
  const int lane = tid & 63, w = tid >> 6;
  const int bl = w * 4 + (lane >> 4);
  const int t = lane & 15;
  const float* xr = xs + bl * 512;
  float s = 0.f, y = 0.f;
  for (int ph = 0; ph < 2; ++ph) {
    __syncthreads();
#pragma unroll
    for (int p = 0; p < 4; ++p) {
      int e4 = p * 256 + tid;  // 1024 float4 = 256 h-rows x 16
      int h = e4 >> 2, c = (e4 & 3) << 2;
      *(float4*)&avs[h * 32 + c] = ((const float4*)attn)[ph * 1024 + e4];
      *(float4*)&avs[h * 32 + 16 + c] = ((const float4*)Vs)[ph * 1024 + e4];
    }
    __syncthreads();
    const float* xp = xr + ph * 256;
#pragma unroll 4
    for (int h = 0; h < 256; ++h) {
      float xv = xp[h];
      s += xv * avs[h * 32 + t];
      y += xv * avs[h * 32 + 16 + t];
    }
  }
  float m = s;
#pragma unroll
  for (int o = 8; o >= 1; o >>= 1) m = fmaxf(m, __shfl_xor(m, o));
  float e = __expf(s - m);
  float sum = e;
#pragma unroll
  for (int o = 8; o >= 1; o >>= 1) sum += __shfl_xor(sum, o);
  float val = (e / sum) * y;
#pragma unroll
  for (int o = 8; o >= 1; o >>= 1) val += __shfl_xor(val, o);
  if (t == 0) out[b0 + bl] = 1.f / (1.f + __expf(-(val + cla_b[0])));
}

// ---------------- launch ----------------
extern "C" void kernel_launch(void* const* d_in, const int* in_sizes, int n_in,
                              void* d_out, int out_size, void* d_ws,
                              size_t ws_size, hipStream_t stream) {
  const float* data = (const float*)d_in[0];   // [8192][5000]
  const float* mlp_w = (const float*)d_in[1];  // [512][5000]
  const float* mlp_b = (const float*)d_in[2];  // [512]
  const float* CM = (const float*)d_in[3];     // [16][512][512]
  const float* attn = (const float*)d_in[4];   // [512][16]
  const float* cla_w = (const float*)d_in[5];  // [512]
  const float* cla_b = (const float*)d_in[6];  // [1]
  float* out = (float*)d_out;                  // [8192]

  char* ws = (char*)d_ws;
  uint16_t* Wb = (uint16_t*)(ws + 0);  // 512*5056*2  =  5,177,344
  float* P = (float*)(ws + 5177344);   // 3*8192*512*4 = 50,331,648
  float* Vs = (float*)(ws + 55508992); // 512*16*4 = 32,768
  // total: 55,541,760 bytes

  // 1) B: cast + zero-pad K 5000 -> 5056 (79*64)
  cast_pad_kernel<<<1264, 256, 0, stream>>>(mlp_w, Wb, 512, 5000, 5056);
  // 2) V = CM . cla_w
  cmv_kernel<<<2048, 256, 0, stream>>>(CM, cla_w, Vs);
  // 3) direct-A GEMM1, z-split into 3 partial buffers (no atomics)
  gemm1_direct<<<768, 256, 0, stream>>>(data, Wb, P);
  // 4) fused partial-sum + bias + softmax + mixture-collapse + sigmoid
  attn_final<<<512, 256, 0, stream>>>(P, mlp_b, attn, Vs, cla_b, out);
}

// Round 6
// 321.960 us; speedup vs baseline: 1.2777x; 1.2565x over previous
//
#include <hip/hip_runtime.h>
#include <hip/hip_bf16.h>
#include <stdint.h>

typedef __bf16 bf16x8 __attribute__((ext_vector_type(8)));
typedef float f32x4 __attribute__((ext_vector_type(4)));

// ---------------- helpers ----------------

__device__ __forceinline__ void gld_lds16(const void* g, void* l) {
  // global -> LDS direct DMA, 16B per lane (wave-uniform base + lane*16).
  __builtin_amdgcn_global_load_lds(
      (const __attribute__((address_space(1))) unsigned int*)g,
      (__attribute__((address_space(3))) unsigned int*)l, 16, 0, 0);
}

__device__ __forceinline__ uint16_t f2bf(float f) {
  uint32_t u = __float_as_uint(f);
  return (uint16_t)((u + 0x7fffu + ((u >> 16) & 1u)) >> 16);
}

__device__ __forceinline__ uint32_t pk2(float a, float b) {
  return (uint32_t)f2bf(a) | ((uint32_t)f2bf(b) << 16);
}

union BF8U {
  uint32_t u[4];
  bf16x8 v;
};

__device__ __forceinline__ bf16x8 pack8(float4 f0, float4 f1) {
  BF8U r;
  r.u[0] = pk2(f0.x, f0.y);
  r.u[1] = pk2(f0.z, f0.w);
  r.u[2] = pk2(f1.x, f1.y);
  r.u[3] = pk2(f1.z, f1.w);
  return r.v;
}

// ---------------- V[h][t] = sum_k CM[t][h][k] * cla_w[k] ----------------
__global__ __launch_bounds__(256) void cmv_kernel(const float* __restrict__ CM,
                                                  const float* __restrict__ cla_w,
                                                  float* __restrict__ Vs) {
  const int tid = threadIdx.x, lane = tid & 63, wid = tid >> 6;
  const int row = blockIdx.x * 4 + wid;  // 0..8191 = t*512 + h
  const float4* src = (const float4*)(CM + (int64_t)row * 512);
  const float4* cw = (const float4*)cla_w;
  float4 a0 = src[lane * 2], a1 = src[lane * 2 + 1];
  float4 w0 = cw[lane * 2], w1 = cw[lane * 2 + 1];
  float s = a0.x * w0.x + a0.y * w0.y + a0.z * w0.z + a0.w * w0.w +
            a1.x * w1.x + a1.y * w1.y + a1.z * w1.z + a1.w * w1.w;
#pragma unroll
  for (int o = 32; o >= 1; o >>= 1) s += __shfl_xor(s, o);
  if (lane == 0) {
    int t = row >> 9, h = row & 511;
    Vs[h * 16 + t] = s;
  }
}

// ---- Gp[z][c][k] = sum_{h in z-chunk} mlp_w[h][k] * U[h][c],  U=[attn|V] ----
// Grid (20, 4): 20 k-blocks of 256 cols (covers padded 5120), 4 h-chunks.
// k >= 5000 writes exact zeros (pad region must annihilate A garbage).
__global__ __launch_bounds__(256) void gmake(const float* __restrict__ mlp_w,
                                             const float* __restrict__ attn,
                                             const float* __restrict__ Vs,
                                             float* __restrict__ Gp) {
  __shared__ float Us[128 * 32];
  const int tid = threadIdx.x;
  const int k = blockIdx.x * 256 + tid;  // 0..5119
  const int z = blockIdx.y;
  const int h0 = z * 128;
#pragma unroll
  for (int p = 0; p < 4; ++p) {
    int e4 = p * 256 + tid;  // 1024 float4 = 128 h x 8 c4
    int h = e4 >> 3, c4 = e4 & 7;
    float4 v;
    if (c4 < 4)
      v = ((const float4*)(attn + (h0 + h) * 16))[c4];
    else
      v = ((const float4*)(Vs + (h0 + h) * 16))[c4 - 4];
    *(float4*)&Us[h * 32 + c4 * 4] = v;
  }
  __syncthreads();
  float acc[32];
#pragma unroll
  for (int c = 0; c < 32; ++c) acc[c] = 0.f;
  const bool valid = (k < 5000);
  const float* wp = mlp_w + (int64_t)h0 * 5000 + (valid ? k : 0);
  for (int h = 0; h < 128; ++h) {
    float a = valid ? wp[(int64_t)h * 5000] : 0.f;
    const float4* ur = (const float4*)&Us[h * 32];
#pragma unroll
    for (int c4 = 0; c4 < 8; ++c4) {
      float4 u = ur[c4];
      acc[c4 * 4 + 0] += a * u.x;
      acc[c4 * 4 + 1] += a * u.y;
      acc[c4 * 4 + 2] += a * u.z;
      acc[c4 * 4 + 3] += a * u.w;
    }
  }
  float* gp = Gp + (int64_t)z * 32 * 5120 + k;
#pragma unroll
  for (int c = 0; c < 32; ++c) gp[(int64_t)c * 5120] = acc[c];
}

// ---------------- Gt[c][k] bf16 = sum_z Gp[z][c][k] ----------------
__global__ void gfinal(const float* __restrict__ Gp,
                       uint16_t* __restrict__ Gt) {
  int e8 = blockIdx.x * 256 + threadIdx.x;  // 20480 threads x 8 elems
  const float4* p = (const float4*)(Gp) + (int64_t)e8 * 2;
  const int64_t pl = 32 * 5120 / 4;  // plane stride in float4
  float4 a0 = p[0], a1 = p[1];
#pragma unroll
  for (int z = 1; z < 4; ++z) {
    float4 b0 = p[z * pl], b1 = p[z * pl + 1];
    a0.x += b0.x; a0.y += b0.y; a0.z += b0.z; a0.w += b0.w;
    a1.x += b1.x; a1.y += b1.y; a1.z += b1.z; a1.w += b1.w;
  }
  uint4 v = make_uint4(pk2(a0.x, a0.y), pk2(a0.z, a0.w),
                       pk2(a1.x, a1.y), pk2(a1.z, a1.w));
  ((uint4*)Gt)[e8] = v;
}

// ---------------- cvec[c] = sum_h mlp_b[h] * U[h][c] ----------------
__global__ __launch_bounds__(256) void cbias(const float* __restrict__ mlp_b,
                                             const float* __restrict__ attn,
                                             const float* __restrict__ Vs,
                                             float* __restrict__ cvec) {
  __shared__ float red[256];
  const int tid = threadIdx.x;
  const int c = tid & 31, g = tid >> 5;  // 8 h-groups
  float acc = 0.f;
  for (int h = g; h < 512; h += 8) {
    float bv = mlp_b[h];
    float uv = (c < 16) ? attn[h * 16 + c] : Vs[h * 16 + (c - 16)];
    acc += bv * uv;
  }
  red[tid] = acc;
  __syncthreads();
  if (tid < 32) {
    float s = 0.f;
#pragma unroll
    for (int g2 = 0; g2 < 8; ++g2) s += red[g2 * 32 + tid];
    cvec[tid] = s;
  }
}

// ------------- megagemm: P[z] = data[8192,5000] @ Gt[32,5120]^T -------------
// The only big-data kernel: A read exactly once (zero tile redundancy since
// N=32 slab lives in LDS). 1024 blocks = 128 m x 8 z; 4 waves x 16 rows;
// Gt z-slab (32x640 bf16 = 40 KB, XOR-swizzled chunks -> conflict-free and
// exactly 4 blocks/CU = 16 waves/CU). A: direct global fp32 -> bf16 pack ->
// MFMA (acc only 8 f32x4 -> low VGPR, deep load pipelining).
__global__ __launch_bounds__(256, 4) void megagemm(
    const float* __restrict__ A,      // [8192][5000] fp32
    const uint16_t* __restrict__ Gt,  // [32][5120] bf16 (zero cols >=5000)
    float* __restrict__ P) {          // [8][8192][32] fp32
  __shared__ __align__(16) uint16_t Gs[32 * 640];  // 40960 B
  const int tid = threadIdx.x;
  const int lane = tid & 63;
  const int w = tid >> 6;
  const int lin = blockIdx.x;
  const int mb = lin & 127;
  const int z = lin >> 7;
  const int m0 = mb * 64;
  const int k0 = z * 640;

  // stage slab: chunk c8 of row r holds source chunk (c8&0x78)|((c8^r)&7)
#pragma unroll
  for (int p = 0; p < 10; ++p) {
    int e = p * 256 + tid;  // 0..2559 = 32 rows x 80 chunks
    int row = e / 80;
    int c8 = e - row * 80;
    int src8 = (c8 & 0x78) | ((c8 ^ row) & 7);
    gld_lds16(Gt + (int64_t)row * 5120 + k0 + src8 * 8, &Gs[e * 8]);
  }
  __syncthreads();

  const int lr = lane & 15;
  const int kg = lane >> 4;
  const int key = lr & 7;
  const float* Arow = A + (int64_t)(m0 + w * 16 + lr) * 5000;

  f32x4 acc0 = {}, acc1 = {};
#pragma unroll
  for (int step = 0; step < 20; ++step) {
    const int col = k0 + step * 32 + kg * 8;  // multiple of 8: never straddles
    const float4* s = (const float4*)(Arow + (col < 5000 ? col : 0));
    float4 f0 = s[0], f1 = s[1];
    bf16x8 af = pack8(f0, f1);  // tail garbage x Gt-zeros = 0
    const int ch = (step * 4 + kg) ^ key;  // un-swizzle
    bf16x8 b0 = *(const bf16x8*)&Gs[lr * 640 + ch * 8];
    bf16x8 b1 = *(const bf16x8*)&Gs[(16 + lr) * 640 + ch * 8];
    acc0 = __builtin_amdgcn_mfma_f32_16x16x32_bf16(af, b0, acc0, 0, 0, 0);
    acc1 = __builtin_amdgcn_mfma_f32_16x16x32_bf16(af, b1, acc1, 0, 0, 0);
  }

  // C/D layout: col = lane&15, row = (lane>>4)*4 + reg
  float* Pz = P + ((int64_t)z * 8192 + m0 + w * 16) * 32;
#pragma unroll
  for (int r = 0; r < 4; ++r) {
    int row = kg * 4 + r;
    Pz[row * 32 + lr] = acc0[r];
    Pz[row * 32 + 16 + lr] = acc1[r];
  }
}

// ------- epilogue: s,y = sum_z P + cvec; softmax(s); sigmoid(w.y+b) -------
// 8 rows/block; 32 lanes per row: c<16 carry s_c, c>=16 carry y_{c-16}.
__global__ __launch_bounds__(256) void epilogue(
    const float* __restrict__ P, const float* __restrict__ cvec,
    const float* __restrict__ cla_b, float* __restrict__ out) {
  const int tid = threadIdx.x;
  const int row = blockIdx.x * 8 + (tid >> 5);
  const int c = tid & 31;
  float s = cvec[c];
#pragma unroll
  for (int z = 0; z < 8; ++z)
    s += P[((int64_t)z * 8192 + row) * 32 + c];
  float yv = __shfl_xor(s, 16);  // partner: for c<16 this is y_c
  float m = s;
#pragma unroll
  for (int o = 8; o >= 1; o >>= 1) m = fmaxf(m, __shfl_xor(m, o));
  float e = __expf(s - m);
  float sum = e;
#pragma unroll
  for (int o = 8; o >= 1; o >>= 1) sum += __shfl_xor(sum, o);
  float val = (e / sum) * yv;
#pragma unroll
  for (int o = 8; o >= 1; o >>= 1) val += __shfl_xor(val, o);
  if (c == 0) out[row] = 1.f / (1.f + __expf(-(val + cla_b[0])));
}

// ---------------- launch ----------------
extern "C" void kernel_launch(void* const* d_in, const int* in_sizes, int n_in,
                              void* d_out, int out_size, void* d_ws,
                              size_t ws_size, hipStream_t stream) {
  const float* data = (const float*)d_in[0];   // [8192][5000]
  const float* mlp_w = (const float*)d_in[1];  // [512][5000]
  const float* mlp_b = (const float*)d_in[2];  // [512]
  const float* CM = (const float*)d_in[3];     // [16][512][512]
  const float* attn = (const float*)d_in[4];   // [512][16]
  const float* cla_w = (const float*)d_in[5];  // [512]
  const float* cla_b = (const float*)d_in[6];  // [1]
  float* out = (float*)d_out;                  // [8192]

  char* ws = (char*)d_ws;
  uint16_t* Gt = (uint16_t*)(ws + 0);     //  32*5120*2      =   327,680
  float* Gp = (float*)(ws + 327680);      //  4*32*5120*4    = 2,621,440
  float* Vs = (float*)(ws + 2949120);     //  512*16*4       =    32,768
  float* cvec = (float*)(ws + 2981888);   //  32*4 (pad 128) =       128
  float* P = (float*)(ws + 2982016);      //  8*8192*32*4    = 8,388,608
  // total: 11,370,624 bytes

  // 1) V = CM . cla_w
  cmv_kernel<<<2048, 256, 0, stream>>>(CM, cla_w, Vs);
  // 2) G partials = mlp_w^T . [attn|V]  (fp32, h-chunked)
  gmake<<<dim3(20, 4), 256, 0, stream>>>(mlp_w, attn, Vs, Gp);
  // 3) Gt = bf16(sum_z Gp), zero-padded to K=5120
  gfinal<<<80, 256, 0, stream>>>(Gp, Gt);
  // 4) constant term from mlp_b
  cbias<<<1, 256, 0, stream>>>(mlp_b, attn, Vs, cvec);
  // 5) the one big pass: [s|y] partials = data @ Gt^T
  megagemm<<<1024, 256, 0, stream>>>(data, Gt, P);
  // 6) softmax + mixture-collapse + sigmoid
  epilogue<<<1024, 256, 0, stream>>>(P, cvec, cla_b, out);
}

// Round 7
// 310.621 us; speedup vs baseline: 1.3244x; 1.0365x over previous
//
#include <hip/hip_runtime.h>
#include <hip/hip_bf16.h>
#include <stdint.h>

typedef __bf16 bf16x8 __attribute__((ext_vector_type(8)));
typedef float f32x4 __attribute__((ext_vector_type(4)));

// ---------------- helpers ----------------

__device__ __forceinline__ void gld_lds16(const void* g, void* l) {
  // global -> LDS direct DMA, 16B per lane (wave-uniform base + lane*16).
  __builtin_amdgcn_global_load_lds(
      (const __attribute__((address_space(1))) unsigned int*)g,
      (__attribute__((address_space(3))) unsigned int*)l, 16, 0, 0);
}

__device__ __forceinline__ uint16_t f2bf(float f) {
  uint32_t u = __float_as_uint(f);
  return (uint16_t)((u + 0x7fffu + ((u >> 16) & 1u)) >> 16);
}

__device__ __forceinline__ uint32_t pk2(float a, float b) {
  return (uint32_t)f2bf(a) | ((uint32_t)f2bf(b) << 16);
}

union BF8U {
  uint32_t u[4];
  bf16x8 v;
};

__device__ __forceinline__ bf16x8 pack8(float4 f0, float4 f1) {
  BF8U r;
  r.u[0] = pk2(f0.x, f0.y);
  r.u[1] = pk2(f0.z, f0.w);
  r.u[2] = pk2(f1.x, f1.y);
  r.u[3] = pk2(f1.z, f1.w);
  return r.v;
}

// ---------------- V[h][t] = sum_k CM[t][h][k] * cla_w[k] ----------------
__global__ __launch_bounds__(256) void cmv_kernel(const float* __restrict__ CM,
                                                  const float* __restrict__ cla_w,
                                                  float* __restrict__ Vs) {
  const int tid = threadIdx.x, lane = tid & 63, wid = tid >> 6;
  const int row = blockIdx.x * 4 + wid;  // 0..8191 = t*512 + h
  const float4* src = (const float4*)(CM + (int64_t)row * 512);
  const float4* cw = (const float4*)cla_w;
  float4 a0 = src[lane * 2], a1 = src[lane * 2 + 1];
  float4 w0 = cw[lane * 2], w1 = cw[lane * 2 + 1];
  float s = a0.x * w0.x + a0.y * w0.y + a0.z * w0.z + a0.w * w0.w +
            a1.x * w1.x + a1.y * w1.y + a1.z * w1.z + a1.w * w1.w;
#pragma unroll
  for (int o = 32; o >= 1; o >>= 1) s += __shfl_xor(s, o);
  if (lane == 0) {
    int t = row >> 9, h = row & 511;
    Vs[h * 16 + t] = s;
  }
}

// -------- gmake3: Gt[c][k] = bf16( sum_h mlp_w[h][k] * U[h][c] ),
//          U = [attn | V];  block 80 computes cvec[c] = sum_h mlp_b[h]*U[h][c].
// Blocks 0..79: 64 k-columns each; 4 waves = 4 h-groups of 128. Each thread
// owns one k and all 32 c (U reads are lane-uniform -> L1/scalar served;
// mlp_w reads coalesced 64x4B). Cross-wave reduce via padded LDS.
__global__ __launch_bounds__(256) void gmake3(
    const float* __restrict__ mlp_w, const float* __restrict__ mlp_b,
    const float* __restrict__ attn, const float* __restrict__ Vs,
    uint16_t* __restrict__ Gt, float* __restrict__ cvec) {
  const int tid = threadIdx.x;
  if (blockIdx.x == 80) {
    __shared__ float red[256];
    const int c = tid & 31, g = tid >> 5;
    float acc = 0.f;
    for (int h = g; h < 512; h += 8) {
      float uv = (c < 16) ? attn[h * 16 + c] : Vs[h * 16 + (c - 16)];
      acc += mlp_b[h] * uv;
    }
    red[tid] = acc;
    __syncthreads();
    if (tid < 32) {
      float s = 0.f;
#pragma unroll
      for (int g2 = 0; g2 < 8; ++g2) s += red[g2 * 32 + tid];
      cvec[tid] = s;
    }
    return;
  }

  __shared__ float Ls[4 * 64 * 33];  // [wave][k][c] padded: 33,792 B
  const int kl = tid & 63;
  const int wv = tid >> 6;
  const int k = blockIdx.x * 64 + kl;
  const bool valid = (k < 5000);
  const float* wp = mlp_w + (valid ? k : 0);
  const int h0 = wv * 128;

  float acc[32];
#pragma unroll
  for (int c = 0; c < 32; ++c) acc[c] = 0.f;

  for (int hh = 0; hh < 128; ++hh) {
    const int h = h0 + hh;
    float a = valid ? wp[(int64_t)h * 5000] : 0.f;
    const float4* ar = (const float4*)(attn + h * 16);
    const float4* vr = (const float4*)(Vs + h * 16);
#pragma unroll
    for (int q = 0; q < 4; ++q) {
      float4 u = ar[q];
      acc[q * 4 + 0] += a * u.x;
      acc[q * 4 + 1] += a * u.y;
      acc[q * 4 + 2] += a * u.z;
      acc[q * 4 + 3] += a * u.w;
    }
#pragma unroll
    for (int q = 0; q < 4; ++q) {
      float4 u = vr[q];
      acc[16 + q * 4 + 0] += a * u.x;
      acc[16 + q * 4 + 1] += a * u.y;
      acc[16 + q * 4 + 2] += a * u.z;
      acc[16 + q * 4 + 3] += a * u.w;
    }
  }
  // write partials: bank = (k*33 + c) % 32 = (k + c) % 32 -> conflict-free
  float* lp = Ls + (wv * 64 + kl) * 33;
#pragma unroll
  for (int c = 0; c < 32; ++c) lp[c] = acc[c];
  __syncthreads();
  // reduce 4 waves: 2048 (k,c) pairs, 8 per thread
#pragma unroll
  for (int p = 0; p < 8; ++p) {
    int e = p * 256 + tid;
    int kk = e >> 5, c = e & 31;
    float s = Ls[kk * 33 + c] + Ls[(64 + kk) * 33 + c] +
              Ls[(128 + kk) * 33 + c] + Ls[(192 + kk) * 33 + c];
    Gt[(int64_t)c * 5120 + blockIdx.x * 64 + kk] = f2bf(s);
  }
}

// ------------- megagemm: P[z] = data[8192,5000] @ Gt[32,5120]^T -------------
// The only big-data kernel: A read exactly once (zero tile redundancy since
// the N=32 slab lives in LDS). 1024 blocks = 128 m x 8 z; 4 waves x 16 rows;
// Gt z-slab (32x640 bf16 = 40 KB, XOR-swizzled chunks, conflict-free, 4
// blocks/CU). A: direct global fp32 -> bf16 pack -> MFMA. z==7 takes the
// clamped tail path (A garbage cols >= 5000 annihilated by Gt zeros).
__global__ __launch_bounds__(256, 4) void megagemm(
    const float* __restrict__ A,      // [8192][5000] fp32
    const uint16_t* __restrict__ Gt,  // [32][5120] bf16 (zero cols >= 5000)
    float* __restrict__ P) {          // [8][8192][32] fp32
  __shared__ __align__(16) uint16_t Gs[32 * 640];  // 40960 B
  const int tid = threadIdx.x;
  const int lane = tid & 63;
  const int w = tid >> 6;
  const int lin = blockIdx.x;
  const int mb = lin & 127;
  const int z = lin >> 7;
  const int m0 = mb * 64;
  const int k0 = z * 640;

  // stage slab: chunk c8 of row r holds source chunk (c8&0x78)|((c8^r)&7)
#pragma unroll
  for (int p = 0; p < 10; ++p) {
    int e = p * 256 + tid;  // 0..2559 = 32 rows x 80 chunks
    int row = e / 80;
    int c8 = e - row * 80;
    int src8 = (c8 & 0x78) | ((c8 ^ row) & 7);
    gld_lds16(Gt + (int64_t)row * 5120 + k0 + src8 * 8, &Gs[e * 8]);
  }
  __syncthreads();

  const int lr = lane & 15;
  const int kg = lane >> 4;
  const int key = lr & 7;
  const float* Arow = A + (int64_t)(m0 + w * 16 + lr) * 5000;

  f32x4 acc0 = {}, acc1 = {};
  if (z < 7) {  // clean path: all columns valid, no clamp
#pragma unroll
    for (int step = 0; step < 20; ++step) {
      const int col = k0 + step * 32 + kg * 8;
      const float4* s = (const float4*)(Arow + col);
      float4 f0 = s[0], f1 = s[1];
      bf16x8 af = pack8(f0, f1);
      const int ch = (step * 4 + kg) ^ key;
      bf16x8 b0 = *(const bf16x8*)&Gs[lr * 640 + ch * 8];
      bf16x8 b1 = *(const bf16x8*)&Gs[(16 + lr) * 640 + ch * 8];
      acc0 = __builtin_amdgcn_mfma_f32_16x16x32_bf16(af, b0, acc0, 0, 0, 0);
      acc1 = __builtin_amdgcn_mfma_f32_16x16x32_bf16(af, b1, acc1, 0, 0, 0);
    }
  } else {  // z == 7: tail, clamp cols >= 5000 (x Gt zeros = 0)
#pragma unroll
    for (int step = 0; step < 20; ++step) {
      const int col = k0 + step * 32 + kg * 8;
      const float4* s = (const float4*)(Arow + (col < 5000 ? col : 0));
      float4 f0 = s[0], f1 = s[1];
      bf16x8 af = pack8(f0, f1);
      const int ch = (step * 4 + kg) ^ key;
      bf16x8 b0 = *(const bf16x8*)&Gs[lr * 640 + ch * 8];
      bf16x8 b1 = *(const bf16x8*)&Gs[(16 + lr) * 640 + ch * 8];
      acc0 = __builtin_amdgcn_mfma_f32_16x16x32_bf16(af, b0, acc0, 0, 0, 0);
      acc1 = __builtin_amdgcn_mfma_f32_16x16x32_bf16(af, b1, acc1, 0, 0, 0);
    }
  }

  // C/D layout: col = lane&15, row = (lane>>4)*4 + reg
  float* Pz = P + ((int64_t)z * 8192 + m0 + w * 16) * 32;
#pragma unroll
  for (int r = 0; r < 4; ++r) {
    int row = kg * 4 + r;
    Pz[row * 32 + lr] = acc0[r];
    Pz[row * 32 + 16 + lr] = acc1[r];
  }
}

// ------- epilogue: s,y = sum_z P + cvec; softmax(s); sigmoid(w.y+b) -------
// 8 rows/block; 32 lanes per row: c<16 carry s_c, c>=16 carry y_{c-16}.
__global__ __launch_bounds__(256) void epilogue(
    const float* __restrict__ P, const float* __restrict__ cvec,
    const float* __restrict__ cla_b, float* __restrict__ out) {
  const int tid = threadIdx.x;
  const int row = blockIdx.x * 8 + (tid >> 5);
  const int c = tid & 31;
  float s = cvec[c];
#pragma unroll
  for (int z = 0; z < 8; ++z)
    s += P[((int64_t)z * 8192 + row) * 32 + c];
  float yv = __shfl_xor(s, 16);  // partner: for c<16 this is y_c
  float m = s;
#pragma unroll
  for (int o = 8; o >= 1; o >>= 1) m = fmaxf(m, __shfl_xor(m, o));
  float e = __expf(s - m);
  float sum = e;
#pragma unroll
  for (int o = 8; o >= 1; o >>= 1) sum += __shfl_xor(sum, o);
  float val = (e / sum) * yv;
#pragma unroll
  for (int o = 8; o >= 1; o >>= 1) val += __shfl_xor(val, o);
  if (c == 0) out[row] = 1.f / (1.f + __expf(-(val + cla_b[0])));
}

// ---------------- launch ----------------
extern "C" void kernel_launch(void* const* d_in, const int* in_sizes, int n_in,
                              void* d_out, int out_size, void* d_ws,
                              size_t ws_size, hipStream_t stream) {
  const float* data = (const float*)d_in[0];   // [8192][5000]
  const float* mlp_w = (const float*)d_in[1];  // [512][5000]
  const float* mlp_b = (const float*)d_in[2];  // [512]
  const float* CM = (const float*)d_in[3];     // [16][512][512]
  const float* attn = (const float*)d_in[4];   // [512][16]
  const float* cla_w = (const float*)d_in[5];  // [512]
  const float* cla_b = (const float*)d_in[6];  // [1]
  float* out = (float*)d_out;                  // [8192]

  char* ws = (char*)d_ws;
  uint16_t* Gt = (uint16_t*)(ws + 0);   //  32*5120*2  =   327,680
  float* Vs = (float*)(ws + 327680);    //  512*16*4   =    32,768
  float* cvec = (float*)(ws + 360448);  //  32*4 (pad) =       128
  float* P = (float*)(ws + 360576);     //  8*8192*32*4= 8,388,608
  // total: 8,749,184 bytes

  // 1) V = CM . cla_w
  cmv_kernel<<<2048, 256, 0, stream>>>(CM, cla_w, Vs);
  // 2) Gt = bf16(mlp_w^T . [attn|V]) + cvec (block 80), single kernel
  gmake3<<<81, 256, 0, stream>>>(mlp_w, mlp_b, attn, Vs, Gt, cvec);
  // 3) the one big pass: [s|y] partials = data @ Gt^T
  megagemm<<<1024, 256, 0, stream>>>(data, Gt, P);
  // 4) softmax + mixture-collapse + sigmoid
  epilogue<<<1024, 256, 0, stream>>>(P, cvec, cla_b, out);
}